// Round 16
// baseline (205.613 us; speedup 1.0000x reference)
//
#include <hip/hip_runtime.h>

typedef unsigned short u16;
typedef __attribute__((ext_vector_type(8))) short bf16x8;
typedef __attribute__((ext_vector_type(4))) float f32x4;
typedef _Float16 half2_t __attribute__((ext_vector_type(2)));

static constexpr int B  = 8;
static constexpr int C  = 64;
static constexpr int CW = 177;
static constexpr int H  = 64, W  = 80;
static constexpr int HP = 68, WP = 84, KC = 192;   // feat padded NHWC
static constexpr int PB = HP * WP * KC;
static constexpr int HA = 36, WA = 44;             // conv5a out padded

__device__ __forceinline__ u16 f2b(float f) {
  union { float f; unsigned u; } v; v.f = f;
  unsigned u = v.u;
  return (u16)((u + 0x7FFF + ((u >> 16) & 1)) >> 16);
}
__device__ __forceinline__ u16 f2h(float f) {
  union { _Float16 h; u16 u; } v; v.h = (_Float16)f; return v.u;
}
__device__ __forceinline__ half2_t h2(unsigned u) {
  union { unsigned u; half2_t h; } v; v.u = u; return v.h;
}
__device__ __forceinline__ float blo(unsigned u) {
  union { unsigned v; float f; } t; t.v = u << 16; return t.f;
}
__device__ __forceinline__ float bhi(unsigned u) {
  union { unsigned v; float f; } t; t.v = u & 0xffff0000u; return t.f;
}
__device__ __forceinline__ unsigned pk2(u16 a, u16 b) {
  return (unsigned)a | ((unsigned)b << 16);
}

// ---------------- fused: pool2 (blocks 0..1023) + setup (rest) ----------------
// A5a/A5b packed: dst = (((tap*4+rg)*6+kc)*64 + kq*16+l15)*8 + s
// A5b1/A5b2 packed: dst = (((tap*4+rg)*2+kc)*64 + kq*16+l15)*8 + s
__global__ __launch_bounds__(256) void setup_pool(
    const float* __restrict__ x0, const float* __restrict__ y0,
    u16* __restrict__ xpT, u16* __restrict__ ypT,
    const float* __restrict__ w1a, const float* __restrict__ w2a,
    const float* __restrict__ w1b, const float* __restrict__ w2b,
    u16* __restrict__ A5a, u16* __restrict__ A5b,
    u16* __restrict__ A5b1, u16* __restrict__ A5b2,
    u16* __restrict__ featP1, u16* __restrict__ haP, u16* __restrict__ featP2) {
  __shared__ u16 lt[80][66];
  int blk0 = blockIdx.x;
  int tid = threadIdx.x;
  if (blk0 < 1024) {
    int sel = blk0 & 1; int h = (blk0 >> 1) & 63; int b = blk0 >> 7;
    const float* in = sel ? y0 : x0;
    u16* out = sel ? ypT : xpT;
#pragma unroll
    for (int i = 0; i < 20; ++i) {
      int e = i * 256 + tid;
      int c = e / 80, w = e % 80;
      const float* p = in + ((size_t)(b * 64 + c) * 128 + 2 * h) * 160 + 2 * w;
      float2 r0 = *(const float2*)p;
      float2 r1 = *(const float2*)(p + 160);
      lt[w][c] = f2h(0.25f * (r0.x + r0.y + r1.x + r1.y));
    }
    __syncthreads();
#pragma unroll
    for (int i = 0; i < 20; ++i) {
      int e = i * 256 + tid;
      int w = e / 64, c = e % 64;
      out[((size_t)(b * H + h) * W + w) * C + c] = lt[w][c];
    }
    return;
  }
  int idx = (blk0 - 1024) * 256 + tid;
  const int n0r = (B * PB) / 8;
  const int n1r = (B * HA * WA * 64) / 8;
  const int n2r = B * 592 * 24;
  const int s1 = 25 * 64 * 192, s2 = 25 * 64 * 64;
  bf16x8 z = 0;
  if (idx < n0r) { ((bf16x8*)featP1)[idx] = z; return; }
  idx -= n0r;
  if (idx < n1r) { ((bf16x8*)haP)[idx] = z; return; }
  idx -= n1r;
  if (idx < n2r) {
    int ch = idx % 24; int pi = (idx / 24) % 592; int b = idx / (24 * 592);
    int row, col;
    if (pi < 336) { int rr = pi / 84; row = (rr < 2) ? rr : rr + 64; col = pi % 84; }
    else { int pj = pi - 336; row = 2 + (pj >> 2); int cc = pj & 3; col = (cc < 2) ? cc : cc + 80; }
    *(bf16x8*)(featP2 + ((size_t)(b * HP + row) * WP + col) * KC + ch * 8) = z;
    return;
  }
  idx -= n2r;
  if (idx < 2 * s1) {
    const float* w = idx < s1 ? w1a : w2a; u16* A = idx < s1 ? A5a : A5b;
    int e = idx % s1;
    int j = e % 192; int i = (e / 192) % 64; int kk = e / (192 * 64);
    int ky = kk / 5, kx = kk % 5;
    float v = (j < CW) ? w[(((size_t)i * CW + j) * 5 + ky) * 5 + kx] : 0.f;
    int rg = i >> 4, l15 = i & 15;
    int kc = j >> 5, r = j & 31, kq = r >> 3, s = r & 7;
    A[(((size_t)(kk * 4 + rg) * 6 + kc) * 64 + kq * 16 + l15) * 8 + s] = f2b(v);
    return;
  }
  idx -= 2 * s1;
  if (idx < 2 * s2) {
    const float* w = idx < s2 ? w1b : w2b; u16* A = idx < s2 ? A5b1 : A5b2;
    int e = idx % s2;
    int j = e % 64; int i = (e / 64) % 64; int kk = e / (64 * 64);
    int ky = kk / 5, kx = kk % 5;
    float v = w[(((size_t)i * 64 + j) * 5 + ky) * 5 + kx];
    int rg = i >> 4, l15 = i & 15;
    int kc = j >> 5, r = j & 31, kq = r >> 3, s = r & 7;
    A[(((size_t)(kk * 4 + rg) * 2 + kc) * 64 + kq * 16 + l15) * 8 + s] = f2b(v);
  }
}

// ---------------- fused: corr row-staged (blocks 0..511) + copy_tr (512..1535) ----------------
__global__ __launch_bounds__(256) void corr_copy(
    const u16* __restrict__ xpT, const u16* __restrict__ ypT,
    const float* __restrict__ x, const float* __restrict__ y,
    u16* __restrict__ featP) {
  __shared__ char sm[40960];
  int blk0 = blockIdx.x;
  int tid = threadIdx.x;
  if (blk0 < 512) {
    int b = blk0 & 7; int h = blk0 >> 3;
    const u16* yb = ypT + (size_t)b * (H * W * C);
    uint4 xv[8];
    {
      const u16* xb = xpT + (((size_t)b * H + h) * W + (tid % 80)) * C;
#pragma unroll
      for (int s = 0; s < 8; ++s) xv[s] = *(const uint4*)(xb + s * 8);
    }
    int w = tid % 80; int og = tid / 80;
    u16* dst = featP + ((size_t)(b * HP + h + 2) * WP + (w + 2)) * KC;
#pragma unroll
    for (int ph = 0; ph < 2; ++ph) {
      const int nrows = ph ? 3 : 4;
      const int nch = nrows * 640;
      if (ph) __syncthreads();
      for (int it = 0; it * 256 + tid < nch; ++it) {
        int idx = it * 256 + tid;
        int row = idx / 640; int rem = idx - row * 640; int q = rem >> 3; int slot = rem & 7;
        int hh = h - 6 + 2 * (ph * 4 + row);
        bf16x8 v = 0;
        if (hh >= 0 && hh < H) v = *(const bf16x8*)(yb + ((size_t)hh * W + q) * C + slot * 8);
        int byte = (idx * 16) ^ ((q & 7) << 4);
        *(bf16x8*)(sm + byte) = v;
      }
      __syncthreads();
      if (tid < 240) {
        const int base = ph ? 28 : 0;
        const int cnt = ph ? 7 : 10;
        const int bound = ph ? 49 : 28;
#pragma unroll
        for (int oi = 0; oi < 10; ++oi) {
          if (oi >= cnt) break;
          int o = base + og * cnt + oi;
          if (o < bound) {
            int rr = o / 7; int dx = (o % 7) * 2 - 6;
            int lr = rr - ph * 4;
            int ww = w + dx;
            float s = 0.f;
            if (ww >= 0 && ww < W) {
#pragma unroll
              for (int sl = 0; sl < 8; ++sl) {
                int byte = (((lr * 640) + ww * 8 + sl) * 16) ^ ((ww & 7) << 4);
                uint4 yv = *(const uint4*)(sm + byte);
                s = __builtin_amdgcn_fdot2(h2(xv[sl].x), h2(yv.x), s, false);
                s = __builtin_amdgcn_fdot2(h2(xv[sl].y), h2(yv.y), s, false);
                s = __builtin_amdgcn_fdot2(h2(xv[sl].z), h2(yv.z), s, false);
                s = __builtin_amdgcn_fdot2(h2(xv[sl].w), h2(yv.w), s, false);
              }
            }
            dst[o] = f2b(s * (1.0f / 64.0f));
          }
        }
      }
    }
    return;
  }
  int blk = blk0 - 512;
  float (*lt)[129] = (float(*)[129])sm;
  int half = blk & 1; int h = (blk >> 1) & 63; int b = blk >> 7;
#pragma unroll
  for (int i = 0; i < 20; ++i) {
    int e = i * 256 + tid;
    int c2 = e / 40, w = e % 40;
    const float* src = (c2 < 64) ? x : y;
    int c = c2 & 63;
    lt[w][c2] = src[((size_t)(b * 64 + c) * H + h) * W + half * 40 + w];
  }
  __syncthreads();
#pragma unroll
  for (int i = 0; i < 20; ++i) {
    int e = i * 256 + tid;
    int wr = e / 128, c = e % 128;
    featP[((size_t)(b * HP + h + 2) * WP + (half * 40 + wr + 2)) * KC + 49 + c] = f2b(lt[wr][c]);
  }
}

// ---------------- per-batch adaptive weights -> MFMA-fragment layout ----------------
__global__ void wx_pack(const float* __restrict__ fv, const float* __restrict__ ww,
                        const float* __restrict__ wb, u16* __restrict__ Apk) {
  int idx = blockIdx.x * blockDim.x + threadIdx.x;
  if (idx >= 9 * 192 * 24) return;
  int j8 = idx % 24; int i = (idx / 24) % 192; int kk = idx / (24 * 192);
  float wwv[8], wbv[8];
#pragma unroll
  for (int jj = 0; jj < 8; ++jj) {
    int j = j8 * 8 + jj;
    if (i < CW && j < CW) {
      size_t o = ((size_t)i * CW + j) * 9 + kk;
      wwv[jj] = ww[o]; wbv[jj] = wb[o];
    } else { wwv[jj] = 0.f; wbv[jj] = 0.f; }
  }
  int rb = i >> 4, il = i & 15;
  int c = j8 >> 3, rem = j8 & 7, half = rem >> 2, kqq = rem & 3;
  size_t dst = (((((size_t)kk * 12 + rb) * 3 + c) * 2 + half) * 64 + kqq * 16 + il) * 8;
  for (int b = 0; b < B; ++b) {
    float f = (i < CW) ? fv[b * CW + i] : 0.f;
    u16 o[8];
#pragma unroll
    for (int jj = 0; jj < 8; ++jj) o[jj] = f2b(f * wwv[jj] + wbv[jj]);
    uint4 v; v.x = pk2(o[0], o[1]); v.y = pk2(o[2], o[3]); v.z = pk2(o[4], o[5]); v.w = pk2(o[6], o[7]);
    *(uint4*)(Apk + (size_t)b * 331776 + dst) = v;
  }
}

// ---------------- adaptive conv v8: 6 waves x FM=2 (3 waves/SIMD), 3-c-chunk dbuf ----------------
__global__ __launch_bounds__(384, 3) void ad_conv_kernel(
    const u16* __restrict__ Apk, const u16* __restrict__ featP, u16* __restrict__ outP) {
  __shared__ u16 lds[2][3 * 84 * 64];              // 2 x 32256 B
  int bid = (int)(blockIdx.x % 8) * 64 + (int)(blockIdx.x / 8);
  int h = bid & 63; int b = bid >> 6;
  int tid = threadIdx.x;
  int lane = tid & 63; int wm = tid >> 6;          // 6 waves = 6 M-groups of 32
  int l15 = lane & 15, kq = lane >> 4;

  f32x4 acc[2][5];
#pragma unroll
  for (int i = 0; i < 2; ++i)
#pragma unroll
    for (int j = 0; j < 5; ++j) acc[i][j] = (f32x4){0.f, 0.f, 0.f, 0.f};

  const u16* fb = featP + (size_t)b * PB;
  const u16* Ab = Apk + (size_t)b * 331776 + (size_t)lane * 8;

  bf16x8 r[6];
  auto load_c = [&](int c) {
#pragma unroll
    for (int it = 0; it < 6; ++it) {
      int idx = it * 384 + tid;
      if (idx < 2016) {
        int row = idx / 672; int rem = idx - row * 672; int q = rem >> 3; int slot = rem & 7;
        r[it] = *(const bf16x8*)(fb + ((size_t)(h + 1 + row) * WP + q) * KC + c * 64 + slot * 8);
      }
    }
  };
  auto write_c = [&](int buf) {
    char* lw = (char*)lds[buf];
#pragma unroll
    for (int it = 0; it < 6; ++it) {
      int idx = it * 384 + tid;
      if (idx < 2016) {
        int q = (idx % 672) >> 3;
        int byte = (idx * 16) ^ ((q & 7) << 4);
        *(bf16x8*)(lw + byte) = r[it];
      }
    }
  };

  load_c(0);
  write_c(0);
  __syncthreads();

#pragma unroll
  for (int c = 0; c < 3; ++c) {
    if (c < 2) load_c(c + 1);
    const char* lb = (const char*)lds[c & 1];
#pragma unroll
    for (int ty = 0; ty < 3; ++ty)
#pragma unroll
      for (int tx = 0; tx < 3; ++tx) {
        const int tap = ty * 3 + tx;
#pragma unroll
        for (int hk = 0; hk < 2; ++hk) {
          bf16x8 av[2], bv[5];
#pragma unroll
          for (int fm = 0; fm < 2; ++fm)
            av[fm] = *(const bf16x8*)(Ab + (size_t)(((tap * 12 + wm * 2 + fm) * 3 + c) * 2 + hk) * 512);
#pragma unroll
          for (int fn = 0; fn < 5; ++fn) {
            int q = fn * 16 + l15 + tx + 1;
            int idx = ty * 672 + q * 8 + hk * 4 + kq;
            int byte = (idx * 16) ^ ((q & 7) << 4);
            bv[fn] = *(const bf16x8*)(lb + byte);
          }
          __builtin_amdgcn_s_setprio(1);
#pragma unroll
          for (int fm = 0; fm < 2; ++fm)
#pragma unroll
            for (int fn = 0; fn < 5; ++fn)
              acc[fm][fn] = __builtin_amdgcn_mfma_f32_16x16x32_bf16(av[fm], bv[fn], acc[fm][fn], 0, 0, 0);
          __builtin_amdgcn_s_setprio(0);
        }
      }
    if (c < 2) {
      write_c((c + 1) & 1);
      __syncthreads();
    }
  }

#pragma unroll
  for (int fm = 0; fm < 2; ++fm) {
    int i0r = wm * 32 + fm * 16 + kq * 4;
#pragma unroll
    for (int fn = 0; fn < 5; ++fn) {
      int ow = fn * 16 + l15;
      u16* dst = outP + ((size_t)(b * HP + h + 2) * WP + (ow + 2)) * KC + i0r;
      uint2 pkv;
      pkv.x = pk2(f2b(fmaxf(acc[fm][fn][0], 0.f)), f2b(fmaxf(acc[fm][fn][1], 0.f)));
      pkv.y = pk2(f2b(fmaxf(acc[fm][fn][2], 0.f)), f2b(fmaxf(acc[fm][fn][3], 0.f)));
      *(uint2*)dst = pkv;
    }
  }
}

// ---------------- conv5 (s2) ky+c split, packed A, dbuf, 1 barrier/chunk ----------------
__global__ __launch_bounds__(128, 3) void conv5_split_kernel(
    const u16* __restrict__ A5, const u16* __restrict__ featP, u16* __restrict__ pa) {
  __shared__ u16 lds[2][84 * 64];
  int bid = (int)(blockIdx.x % 8) * 160 + (int)(blockIdx.x / 8);
  int rp = bid % 16; int ty = (bid / 16) % 5; int csel = (bid / 80) % 2; int b = bid / 160;
  int r0 = rp * 2;
  int kc0 = csel * 3;
  int tid = threadIdx.x;
  int lane = tid & 63; int wm = tid >> 6;          // 2 waves
  int l15 = lane & 15, kq = lane >> 4;

  f32x4 acc[2][5];
#pragma unroll
  for (int i = 0; i < 2; ++i)
#pragma unroll
    for (int j = 0; j < 5; ++j) acc[i][j] = (f32x4){0.f, 0.f, 0.f, 0.f};

  const u16* fb = featP + (size_t)b * PB;
  int rowg0 = 2 * r0 + ty;

  bf16x8 r[6];
  auto load_chunk = [&](int kc) {
#pragma unroll
    for (int it = 0; it < 6; ++it) {
      int idx = it * 128 + tid;
      if (idx < 672) {
        int slot = idx & 3; int q = (idx >> 2) % 84; int row = idx / 336;
        r[it] = *(const bf16x8*)(fb + ((size_t)(rowg0 + 2 * row) * WP + q) * KC + kc * 32 + slot * 8);
      }
    }
  };
  auto write_chunk = [&](int buf) {
    char* lw = (char*)lds[buf];
#pragma unroll
    for (int it = 0; it < 6; ++it) {
      int idx = it * 128 + tid;
      if (idx < 672) {
        int q = (idx >> 2) % 84;
        int byte = (idx * 16) ^ ((q & 7) << 4);
        *(bf16x8*)(lw + byte) = r[it];
      }
    }
  };

  load_chunk(kc0);
  write_chunk(0);
  __syncthreads();

#pragma unroll
  for (int k = 0; k < 3; ++k) {
    int kc = kc0 + k;
    if (k < 2) load_chunk(kc + 1);
    const char* lb = (const char*)lds[k & 1];
#pragma unroll
    for (int tx = 0; tx < 5; ++tx) {
      int tap = ty * 5 + tx;
      bf16x8 av[2], bv[5];
#pragma unroll
      for (int fm = 0; fm < 2; ++fm)
        av[fm] = *(const bf16x8*)(A5 + ((size_t)((tap * 4 + wm * 2 + fm) * 6 + kc)) * 512 + lane * 8);
#pragma unroll
      for (int fn = 0; fn < 5; ++fn) {
        int p = fn * 16 + l15;
        int orow = p / 40, ocol = p % 40;
        int q = ocol * 2 + tx;
        int byte = (((orow * 84 + q) * 4 + kq) * 16) ^ ((q & 7) << 4);
        bv[fn] = *(const bf16x8*)(lb + byte);
      }
      __builtin_amdgcn_s_setprio(1);
#pragma unroll
      for (int fm = 0; fm < 2; ++fm)
#pragma unroll
        for (int fn = 0; fn < 5; ++fn)
          acc[fm][fn] = __builtin_amdgcn_mfma_f32_16x16x32_bf16(av[fm], bv[fn], acc[fm][fn], 0, 0, 0);
      __builtin_amdgcn_s_setprio(0);
    }
    if (k < 2) {
      write_chunk((k + 1) & 1);
      __syncthreads();
    }
  }
  int slot10 = csel * 5 + ty;
#pragma unroll
  for (int fm = 0; fm < 2; ++fm) {
    int oc0 = wm * 32 + fm * 16 + kq * 4;
#pragma unroll
    for (int fn = 0; fn < 5; ++fn) {
      int p = fn * 16 + l15;
      int orow = r0 + p / 40, ocol = p % 40;
      u16* dst = pa + (((((size_t)slot10 * B + b) * 32 + orow) * 40 + ocol) * 64) + oc0;
      uint2 pkv;
      pkv.x = pk2(f2b(acc[fm][fn][0]), f2b(acc[fm][fn][1]));
      pkv.y = pk2(f2b(acc[fm][fn][2]), f2b(acc[fm][fn][3]));
      *(uint2*)dst = pkv;
    }
  }
}

// ---------------- combine 10 bf16 partials -> relu -> bf16 haP ----------------
__global__ void combine10(const u16* __restrict__ pa, u16* __restrict__ haP) {
  int idx = blockIdx.x * blockDim.x + threadIdx.x;
  if (idx >= B * 32 * 40 * 8) return;
  int c8 = idx & 7; int t = idx >> 3;
  int ocol = t % 40; t /= 40; int orow = t % 32; int b = t / 32;
  float s[8];
#pragma unroll
  for (int k = 0; k < 8; ++k) s[k] = 0.f;
#pragma unroll
  for (int sl = 0; sl < 10; ++sl) {
    const u16* p = pa + ((((size_t)sl * B + b) * 32 + orow) * 40 + ocol) * 64 + c8 * 8;
    uint4 v = *(const uint4*)p;
    s[0] += blo(v.x); s[1] += bhi(v.x); s[2] += blo(v.y); s[3] += bhi(v.y);
    s[4] += blo(v.z); s[5] += bhi(v.z); s[6] += blo(v.w); s[7] += bhi(v.w);
  }
  uint4 o;
  o.x = pk2(f2b(fmaxf(s[0], 0.f)), f2b(fmaxf(s[1], 0.f)));
  o.y = pk2(f2b(fmaxf(s[2], 0.f)), f2b(fmaxf(s[3], 0.f)));
  o.z = pk2(f2b(fmaxf(s[4], 0.f)), f2b(fmaxf(s[5], 0.f)));
  o.w = pk2(f2b(fmaxf(s[6], 0.f)), f2b(fmaxf(s[7], 0.f)));
  *(uint4*)(haP + ((size_t)(b * HA + orow + 2) * WA + (ocol + 2)) * 64 + c8 * 8) = o;
}

// ---------------- conv5b: packed A, fp32 NCHW out ----------------
__global__ __launch_bounds__(256) void conv5b_kernel(
    const u16* __restrict__ A, const u16* __restrict__ haP, float* __restrict__ outF) {
  int bid = (int)(blockIdx.x % 8) * 20 + (int)(blockIdx.x / 8);
  int mt = bid % 2; int nt = (bid / 2) % 10; int b = bid / 20;
  int lane = threadIdx.x & 63; int wv = threadIdx.x >> 6;
  int wm = wv >> 1, wn = wv & 1;
  int l15 = lane & 15, kq = lane >> 4;

  f32x4 acc = (f32x4){0.f, 0.f, 0.f, 0.f};
  int p = nt * 32 + wn * 16 + l15;
  int oh = p / 20, ow = p % 20;
  const u16* fb = haP + (size_t)b * (HA * WA * 64) + kq * 8;

  for (int kc = 0; kc < 2; ++kc) {
#pragma unroll
    for (int ty = 0; ty < 5; ++ty)
#pragma unroll
      for (int tx = 0; tx < 5; ++tx) {
        int tap = ty * 5 + tx;
        bf16x8 av = *(const bf16x8*)(A + ((size_t)((tap * 4 + mt * 2 + wm) * 2 + kc)) * 512 + lane * 8);
        int hi = oh * 2 + ty, wi = ow * 2 + tx;
        bf16x8 bv = *(const bf16x8*)(fb + (size_t)(hi * WA + wi) * 64 + kc * 32);
        acc = __builtin_amdgcn_mfma_f32_16x16x32_bf16(av, bv, acc, 0, 0, 0);
      }
  }

  int oc0 = mt * 32 + wm * 16 + kq * 4;
#pragma unroll
  for (int r = 0; r < 4; ++r) {
    float v = fmaxf(acc[r], 0.f);
    outF[(((size_t)b * 64 + oc0 + r) * 16 + oh) * 20 + ow] = v;
  }
}

// ---------------- conv3+mean fold, step 1: 9-bin tap sums (wave reduce) ----------------
__global__ void tapsum_kernel(const float* __restrict__ hb, float* __restrict__ Sm) {
  int b = blockIdx.x >> 6; int ic = blockIdx.x & 63; int lane = threadIdx.x;
  const float* p = hb + ((size_t)(b * 64 + ic)) * 320;
  float s[9];
#pragma unroll
  for (int t = 0; t < 9; ++t) s[t] = 0.f;
  for (int i = lane; i < 320; i += 64) {
    int ih = i / 20, iw = i % 20;
    float v = p[i];
#pragma unroll
    for (int ky = 0; ky < 3; ++ky) {
      int t2 = ih + 1 - ky;
      if (t2 < 0 || t2 > 14 || (t2 & 1)) continue;
#pragma unroll
      for (int kx = 0; kx < 3; ++kx) {
        int t3 = iw + 1 - kx;
        if (t3 < 0 || t3 > 18 || (t3 & 1)) continue;
        s[ky * 3 + kx] += v;
      }
    }
  }
#pragma unroll
  for (int t = 0; t < 9; ++t)
#pragma unroll
    for (int off = 32; off > 0; off >>= 1) s[t] += __shfl_down(s[t], off);
  if (lane == 0) {
#pragma unroll
    for (int t = 0; t < 9; ++t) Sm[(b * 64 + ic) * 9 + t] = s[t];
  }
}

// ---------------- fv GEMV (branch 1) ----------------
__global__ void gemv_fv(const float* __restrict__ w3, const float* __restrict__ Sm,
                        float* __restrict__ fv, int OC) {
  int o = blockIdx.x % OC; int b = blockIdx.x / OC; int lane = threadIdx.x;
  const float* wp = w3 + ((size_t)o * 64 + lane) * 9;
  const float* sp = Sm + ((size_t)b * 64 + lane) * 9;
  float acc = 0.f;
#pragma unroll
  for (int t = 0; t < 9; ++t) acc += wp[t] * sp[t];
#pragma unroll
  for (int off = 32; off > 0; off >>= 1) acc += __shfl_down(acc, off);
  if (lane == 0) fv[b * OC + o] = acc * (1.0f / 80.0f);
}

// ---------------- branch-2 gemv fused with final output ----------------
__global__ void gemv_final(const float* __restrict__ w3, const float* __restrict__ Sm,
                           const float* __restrict__ ww, const float* __restrict__ wb,
                           float* __restrict__ out) {
  int o = blockIdx.x & 63; int b = blockIdx.x >> 6; int lane = threadIdx.x;
  const float* wp = w3 + ((size_t)o * 64 + lane) * 9;
  const float* sp = Sm + ((size_t)b * 64 + lane) * 9;
  float acc = 0.f;
#pragma unroll
  for (int t = 0; t < 9; ++t) acc += wp[t] * sp[t];
#pragma unroll
  for (int off = 32; off > 0; off >>= 1) acc += __shfl_down(acc, off);
  float fvv = __shfl(acc, 0) * (1.0f / 80.0f);
  const float* wwp = ww + (size_t)o * 576;
  const float* wbp = wb + (size_t)o * 576;
  float* op = out + ((size_t)(b * 64 + o)) * 576;
#pragma unroll
  for (int k = 0; k < 9; ++k)
    op[k * 64 + lane] = fvv * wwp[k * 64 + lane] + wbp[k * 64 + lane];
}

extern "C" void kernel_launch(void* const* d_in, const int* in_sizes, int n_in,
                              void* d_out, int out_size, void* d_ws, size_t ws_size,
                              hipStream_t stream) {
  const float* x0    = (const float*)d_in[0];
  const float* y0    = (const float*)d_in[1];
  const float* x     = (const float*)d_in[2];
  const float* y     = (const float*)d_in[3];
  const float* w1a   = (const float*)d_in[4];
  const float* w1b   = (const float*)d_in[5];
  const float* w1c   = (const float*)d_in[6];
  const float* w2a   = (const float*)d_in[7];
  const float* w2b   = (const float*)d_in[8];
  const float* w2c   = (const float*)d_in[9];
  const float* wx_w  = (const float*)d_in[10];
  const float* wx_b  = (const float*)d_in[11];
  const float* wxf_w = (const float*)d_in[12];
  const float* wxf_b = (const float*)d_in[13];
  float* out = (float*)d_out;

  char* base = (char*)d_ws;
  size_t off = 0;
  auto take = [&](size_t bytes) -> char* {
    char* p = base + off; off += (bytes + 255) & ~(size_t)255; return p;
  };
  u16*   featP1 = (u16*)take((size_t)B * PB * 2);                 // 17.55 MB
  u16*   featP2 = (u16*)take((size_t)B * PB * 2);                 // 17.55 MB
  u16*   paAwx  = (u16*)take((size_t)10 * B * 32 * 40 * 64 * 2);  // 13.1 MB
  u16*   pa     = paAwx;
  u16*   Apk    = paAwx;
  u16*   xpT    = paAwx;                                           // alias: pools consumed before pa written
  u16*   ypT    = paAwx + (size_t)B * H * W * C;
  u16*   A5a    = (u16*)take((size_t)25 * 64 * 192 * 2);
  u16*   A5b    = (u16*)take((size_t)25 * 64 * 192 * 2);
  u16*   A5b1   = (u16*)take((size_t)25 * 64 * 64 * 2);
  u16*   A5b2   = (u16*)take((size_t)25 * 64 * 64 * 2);
  u16*   haP    = (u16*)take((size_t)B * HA * WA * 64 * 2);
  float* hb     = (float*)take((size_t)B * 64 * 320 * 4);
  float* Sm     = (float*)take((size_t)B * 64 * 9 * 4);
  float* fv1    = (float*)take((size_t)B * CW * 4);
  if (off > ws_size) return;

  const int TB = 256;

  {
    int nsetup = (B * PB) / 8 + (B * HA * WA * 64) / 8 + B * 592 * 24
               + 2 * 25 * 64 * 192 + 2 * 25 * 64 * 64;
    int grid = 1024 + (nsetup + TB - 1) / TB;
    setup_pool<<<grid, TB, 0, stream>>>(x0, y0, xpT, ypT,
        w1a, w2a, w1b, w2b, A5a, A5b, A5b1, A5b2, featP1, haP, featP2);
  }
  corr_copy<<<512 + 1024, TB, 0, stream>>>(xpT, ypT, x, y, featP1);

  // ---- branch 1 ----
  conv5_split_kernel<<<1280, 128, 0, stream>>>(A5a, featP1, pa);
  combine10<<<(B * 32 * 40 * 8 + TB - 1) / TB, TB, 0, stream>>>(pa, haP);
  conv5b_kernel<<<160, TB, 0, stream>>>(A5b1, haP, hb);
  tapsum_kernel<<<B * 64, 64, 0, stream>>>(hb, Sm);
  gemv_fv<<<B * CW, 64, 0, stream>>>(w1c, Sm, fv1, CW);

  // ---- adaptive conv ----
  wx_pack<<<(9 * 192 * 24 + TB - 1) / TB, TB, 0, stream>>>(fv1, wx_w, wx_b, Apk);
  ad_conv_kernel<<<64 * B, 384, 0, stream>>>(Apk, featP1, featP2);

  // ---- branch 2 ----
  conv5_split_kernel<<<1280, 128, 0, stream>>>(A5b, featP2, pa);
  combine10<<<(B * 32 * 40 * 8 + TB - 1) / TB, TB, 0, stream>>>(pa, haP);
  conv5b_kernel<<<160, TB, 0, stream>>>(A5b2, haP, hb);
  tapsum_kernel<<<B * 64, 64, 0, stream>>>(hb, Sm);
  gemv_final<<<B * 64, 64, 0, stream>>>(w2c, Sm, wxf_w, wxf_b, out);
}

// Round 17
// 172.668 us; speedup vs baseline: 1.1908x; 1.1908x over previous
//
#include <hip/hip_runtime.h>

typedef unsigned short u16;
typedef __attribute__((ext_vector_type(8))) short bf16x8;
typedef __attribute__((ext_vector_type(4))) float f32x4;
typedef _Float16 half2_t __attribute__((ext_vector_type(2)));

static constexpr int B  = 8;
static constexpr int C  = 64;
static constexpr int CW = 177;
static constexpr int H  = 64, W  = 80;
static constexpr int HP = 68, WP = 84, KC = 192;   // feat padded NHWC
static constexpr int PB = HP * WP * KC;
static constexpr int HA = 36, WA = 44;             // conv5a out padded

__device__ __forceinline__ u16 f2b(float f) {
  union { float f; unsigned u; } v; v.f = f;
  unsigned u = v.u;
  return (u16)((u + 0x7FFF + ((u >> 16) & 1)) >> 16);
}
__device__ __forceinline__ u16 f2h(float f) {
  union { _Float16 h; u16 u; } v; v.h = (_Float16)f; return v.u;
}
__device__ __forceinline__ half2_t h2(unsigned u) {
  union { unsigned u; half2_t h; } v; v.u = u; return v.h;
}
__device__ __forceinline__ float blo(unsigned u) {
  union { unsigned v; float f; } t; t.v = u << 16; return t.f;
}
__device__ __forceinline__ float bhi(unsigned u) {
  union { unsigned v; float f; } t; t.v = u & 0xffff0000u; return t.f;
}
__device__ __forceinline__ unsigned pk2(u16 a, u16 b) {
  return (unsigned)a | ((unsigned)b << 16);
}

// ---------------- fused: pool2 (blocks 0..1023) + setup (rest) ----------------
__global__ __launch_bounds__(256) void setup_pool(
    const float* __restrict__ x0, const float* __restrict__ y0,
    u16* __restrict__ xpT, u16* __restrict__ ypT,
    const float* __restrict__ w1a, const float* __restrict__ w2a,
    const float* __restrict__ w1b, const float* __restrict__ w2b,
    u16* __restrict__ A5a, u16* __restrict__ A5b,
    u16* __restrict__ A5b1, u16* __restrict__ A5b2,
    u16* __restrict__ featP1, u16* __restrict__ haP, u16* __restrict__ featP2) {
  __shared__ u16 lt[80][66];
  int blk0 = blockIdx.x;
  int tid = threadIdx.x;
  if (blk0 < 1024) {
    int sel = blk0 & 1; int h = (blk0 >> 1) & 63; int b = blk0 >> 7;
    const float* in = sel ? y0 : x0;
    u16* out = sel ? ypT : xpT;
#pragma unroll
    for (int i = 0; i < 20; ++i) {
      int e = i * 256 + tid;
      int c = e / 80, w = e % 80;
      const float* p = in + ((size_t)(b * 64 + c) * 128 + 2 * h) * 160 + 2 * w;
      float2 r0 = *(const float2*)p;
      float2 r1 = *(const float2*)(p + 160);
      lt[w][c] = f2h(0.25f * (r0.x + r0.y + r1.x + r1.y));
    }
    __syncthreads();
#pragma unroll
    for (int i = 0; i < 20; ++i) {
      int e = i * 256 + tid;
      int w = e / 64, c = e % 64;
      out[((size_t)(b * H + h) * W + w) * C + c] = lt[w][c];
    }
    return;
  }
  int idx = (blk0 - 1024) * 256 + tid;
  const int n0r = (B * PB) / 8;
  const int n1r = (B * HA * WA * 64) / 8;
  const int n2r = B * 592 * 24;
  const int s1 = 25 * 64 * 192, s2 = 25 * 64 * 64;
  bf16x8 z = 0;
  if (idx < n0r) { ((bf16x8*)featP1)[idx] = z; return; }
  idx -= n0r;
  if (idx < n1r) { ((bf16x8*)haP)[idx] = z; return; }
  idx -= n1r;
  if (idx < n2r) {
    int ch = idx % 24; int pi = (idx / 24) % 592; int b = idx / (24 * 592);
    int row, col;
    if (pi < 336) { int rr = pi / 84; row = (rr < 2) ? rr : rr + 64; col = pi % 84; }
    else { int pj = pi - 336; row = 2 + (pj >> 2); int cc = pj & 3; col = (cc < 2) ? cc : cc + 80; }
    *(bf16x8*)(featP2 + ((size_t)(b * HP + row) * WP + col) * KC + ch * 8) = z;
    return;
  }
  idx -= n2r;
  if (idx < 2 * s1) {
    const float* w = idx < s1 ? w1a : w2a; u16* A = idx < s1 ? A5a : A5b;
    int e = idx % s1;
    int j = e % 192; int i = (e / 192) % 64; int kk = e / (192 * 64);
    int ky = kk / 5, kx = kk % 5;
    float v = (j < CW) ? w[(((size_t)i * CW + j) * 5 + ky) * 5 + kx] : 0.f;
    A[e] = f2b(v);
    return;
  }
  idx -= 2 * s1;
  if (idx < 2 * s2) {
    const float* w = idx < s2 ? w1b : w2b; u16* A = idx < s2 ? A5b1 : A5b2;
    int e = idx % s2;
    int j = e % 64; int i = (e / 64) % 64; int kk = e / (64 * 64);
    int ky = kk / 5, kx = kk % 5;
    A[e] = f2b(w[(((size_t)i * 64 + j) * 5 + ky) * 5 + kx]);
  }
}

// ---------------- fused: corr row-staged (blocks 0..511) + copy_tr (512..1535) ----------------
__global__ __launch_bounds__(256) void corr_copy(
    const u16* __restrict__ xpT, const u16* __restrict__ ypT,
    const float* __restrict__ x, const float* __restrict__ y,
    u16* __restrict__ featP) {
  __shared__ char sm[40960];
  int blk0 = blockIdx.x;
  int tid = threadIdx.x;
  if (blk0 < 512) {
    int b = blk0 & 7; int h = blk0 >> 3;
    const u16* yb = ypT + (size_t)b * (H * W * C);
    uint4 xv[8];
    {
      const u16* xb = xpT + (((size_t)b * H + h) * W + (tid % 80)) * C;
#pragma unroll
      for (int s = 0; s < 8; ++s) xv[s] = *(const uint4*)(xb + s * 8);
    }
    int w = tid % 80; int og = tid / 80;
    u16* dst = featP + ((size_t)(b * HP + h + 2) * WP + (w + 2)) * KC;
#pragma unroll
    for (int ph = 0; ph < 2; ++ph) {
      const int nrows = ph ? 3 : 4;
      const int nch = nrows * 640;
      if (ph) __syncthreads();
      for (int it = 0; it * 256 + tid < nch; ++it) {
        int idx = it * 256 + tid;
        int row = idx / 640; int rem = idx - row * 640; int q = rem >> 3; int slot = rem & 7;
        int hh = h - 6 + 2 * (ph * 4 + row);
        bf16x8 v = 0;
        if (hh >= 0 && hh < H) v = *(const bf16x8*)(yb + ((size_t)hh * W + q) * C + slot * 8);
        int byte = (idx * 16) ^ ((q & 7) << 4);
        *(bf16x8*)(sm + byte) = v;
      }
      __syncthreads();
      if (tid < 240) {
        const int base = ph ? 28 : 0;
        const int cnt = ph ? 7 : 10;
        const int bound = ph ? 49 : 28;
#pragma unroll
        for (int oi = 0; oi < 10; ++oi) {
          if (oi >= cnt) break;
          int o = base + og * cnt + oi;
          if (o < bound) {
            int rr = o / 7; int dx = (o % 7) * 2 - 6;
            int lr = rr - ph * 4;
            int ww = w + dx;
            float s = 0.f;
            if (ww >= 0 && ww < W) {
#pragma unroll
              for (int sl = 0; sl < 8; ++sl) {
                int byte = (((lr * 640) + ww * 8 + sl) * 16) ^ ((ww & 7) << 4);
                uint4 yv = *(const uint4*)(sm + byte);
                s = __builtin_amdgcn_fdot2(h2(xv[sl].x), h2(yv.x), s, false);
                s = __builtin_amdgcn_fdot2(h2(xv[sl].y), h2(yv.y), s, false);
                s = __builtin_amdgcn_fdot2(h2(xv[sl].z), h2(yv.z), s, false);
                s = __builtin_amdgcn_fdot2(h2(xv[sl].w), h2(yv.w), s, false);
              }
            }
            dst[o] = f2b(s * (1.0f / 64.0f));
          }
        }
      }
    }
    return;
  }
  int blk = blk0 - 512;
  float (*lt)[129] = (float(*)[129])sm;
  int half = blk & 1; int h = (blk >> 1) & 63; int b = blk >> 7;
#pragma unroll
  for (int i = 0; i < 20; ++i) {
    int e = i * 256 + tid;
    int c2 = e / 40, w = e % 40;
    const float* src = (c2 < 64) ? x : y;
    int c = c2 & 63;
    lt[w][c2] = src[((size_t)(b * 64 + c) * H + h) * W + half * 40 + w];
  }
  __syncthreads();
#pragma unroll
  for (int i = 0; i < 20; ++i) {
    int e = i * 256 + tid;
    int wr = e / 128, c = e % 128;
    featP[((size_t)(b * HP + h + 2) * WP + (half * 40 + wr + 2)) * KC + 49 + c] = f2b(lt[wr][c]);
  }
}

// ---------------- per-batch adaptive weights -> MFMA-fragment layout ----------------
__global__ void wx_pack(const float* __restrict__ fv, const float* __restrict__ ww,
                        const float* __restrict__ wb, u16* __restrict__ Apk) {
  int idx = blockIdx.x * blockDim.x + threadIdx.x;
  if (idx >= 9 * 192 * 24) return;
  int j8 = idx % 24; int i = (idx / 24) % 192; int kk = idx / (24 * 192);
  float wwv[8], wbv[8];
#pragma unroll
  for (int jj = 0; jj < 8; ++jj) {
    int j = j8 * 8 + jj;
    if (i < CW && j < CW) {
      size_t o = ((size_t)i * CW + j) * 9 + kk;
      wwv[jj] = ww[o]; wbv[jj] = wb[o];
    } else { wwv[jj] = 0.f; wbv[jj] = 0.f; }
  }
  int rb = i >> 4, il = i & 15;
  int c = j8 >> 3, rem = j8 & 7, half = rem >> 2, kqq = rem & 3;
  size_t dst = (((((size_t)kk * 12 + rb) * 3 + c) * 2 + half) * 64 + kqq * 16 + il) * 8;
  for (int b = 0; b < B; ++b) {
    float f = (i < CW) ? fv[b * CW + i] : 0.f;
    u16 o[8];
#pragma unroll
    for (int jj = 0; jj < 8; ++jj) o[jj] = f2b(f * wwv[jj] + wbv[jj]);
    uint4 v; v.x = pk2(o[0], o[1]); v.y = pk2(o[2], o[3]); v.z = pk2(o[4], o[5]); v.w = pk2(o[6], o[7]);
    *(uint4*)(Apk + (size_t)b * 331776 + dst) = v;
  }
}

// ---------------- adaptive conv v6: LDS B dbuf (9 fine stages), fragment-packed A, setprio ----------------
__global__ __launch_bounds__(256, 2) void ad_conv_kernel(
    const u16* __restrict__ Apk, const u16* __restrict__ featP, u16* __restrict__ outP) {
  __shared__ u16 lds[2][84 * 64];                  // 2 x 10.5 KB
  int bid = (int)(blockIdx.x % 8) * 64 + (int)(blockIdx.x / 8);
  int h = bid & 63; int b = bid >> 6;
  int tid = threadIdx.x;
  int lane = tid & 63; int wm = tid >> 6;          // 4 waves = 4 M-groups
  int l15 = lane & 15, kq = lane >> 4;

  f32x4 acc[3][5];
#pragma unroll
  for (int i = 0; i < 3; ++i)
#pragma unroll
    for (int j = 0; j < 5; ++j) acc[i][j] = (f32x4){0.f, 0.f, 0.f, 0.f};

  const u16* fb = featP + (size_t)b * PB;
  const u16* Ab = Apk + (size_t)b * 331776 + (size_t)lane * 8;

  int i0 = tid, i1 = tid + 256, i2 = tid + 512;
  int q0 = i0 >> 3, s0 = i0 & 7;
  int q1 = i1 >> 3, s1 = i1 & 7;
  int q2 = i2 >> 3, s2 = i2 & 7;
  int w0 = (i0 * 16) ^ ((q0 & 7) << 4);
  int w1 = (i1 * 16) ^ ((q1 & 7) << 4);
  int w2 = (i2 * 16) ^ ((q2 & 7) << 4);
  bool a2 = i2 < 672;

  bf16x8 r0, r1, r2;
  {
    const u16* g = fb + ((size_t)(h + 1) * WP) * KC;
    r0 = *(const bf16x8*)(g + (size_t)q0 * KC + s0 * 8);
    r1 = *(const bf16x8*)(g + (size_t)q1 * KC + s1 * 8);
    if (a2) r2 = *(const bf16x8*)(g + (size_t)q2 * KC + s2 * 8);
    char* lw = (char*)lds[0];
    *(bf16x8*)(lw + w0) = r0;
    *(bf16x8*)(lw + w1) = r1;
    if (a2) *(bf16x8*)(lw + w2) = r2;
  }
  __syncthreads();

#pragma unroll
  for (int s = 0; s < 9; ++s) {
    const int c = s / 3, ty = s % 3;
    if (s < 8) {
      const int cn = (s + 1) / 3, tyn = (s + 1) % 3;
      const u16* g = fb + ((size_t)(h + 1 + tyn) * WP) * KC + cn * 64;
      r0 = *(const bf16x8*)(g + (size_t)q0 * KC + s0 * 8);
      r1 = *(const bf16x8*)(g + (size_t)q1 * KC + s1 * 8);
      if (a2) r2 = *(const bf16x8*)(g + (size_t)q2 * KC + s2 * 8);
    }
    const char* lb = (const char*)lds[s & 1];
#pragma unroll
    for (int tx = 0; tx < 3; ++tx) {
      const int tap = ty * 3 + tx;
#pragma unroll
      for (int hk = 0; hk < 2; ++hk) {
        bf16x8 av[3], bv[5];
#pragma unroll
        for (int fm = 0; fm < 3; ++fm)
          av[fm] = *(const bf16x8*)(Ab + (size_t)(((tap * 12 + wm * 3 + fm) * 3 + c) * 2 + hk) * 512);
#pragma unroll
        for (int fn = 0; fn < 5; ++fn) {
          int q = fn * 16 + l15 + tx + 1;
          int byte = ((q * 8 + hk * 4 + kq) * 16) ^ ((q & 7) << 4);
          bv[fn] = *(const bf16x8*)(lb + byte);
        }
        __builtin_amdgcn_s_setprio(1);
#pragma unroll
        for (int fm = 0; fm < 3; ++fm)
#pragma unroll
          for (int fn = 0; fn < 5; ++fn)
            acc[fm][fn] = __builtin_amdgcn_mfma_f32_16x16x32_bf16(av[fm], bv[fn], acc[fm][fn], 0, 0, 0);
        __builtin_amdgcn_s_setprio(0);
      }
    }
    if (s < 8) {
      char* lw = (char*)lds[(s + 1) & 1];
      *(bf16x8*)(lw + w0) = r0;
      *(bf16x8*)(lw + w1) = r1;
      if (a2) *(bf16x8*)(lw + w2) = r2;
      __syncthreads();
    }
  }

#pragma unroll
  for (int fm = 0; fm < 3; ++fm) {
    int i0r = wm * 48 + fm * 16 + kq * 4;
#pragma unroll
    for (int fn = 0; fn < 5; ++fn) {
      int ow = fn * 16 + l15;
      u16* dst = outP + ((size_t)(b * HP + h + 2) * WP + (ow + 2)) * KC + i0r;
      uint2 pkv;
      pkv.x = pk2(f2b(fmaxf(acc[fm][fn][0], 0.f)), f2b(fmaxf(acc[fm][fn][1], 0.f)));
      pkv.y = pk2(f2b(fmaxf(acc[fm][fn][2], 0.f)), f2b(fmaxf(acc[fm][fn][3], 0.f)));
      *(uint2*)dst = pkv;
    }
  }
}

// ---------------- conv5 (s2) ky+c split, dbuf reg-staged, 1 barrier/chunk ----------------
__global__ __launch_bounds__(128, 3) void conv5_split_kernel(
    const u16* __restrict__ A5, const u16* __restrict__ featP, u16* __restrict__ pa) {
  __shared__ u16 lds[2][84 * 64];
  int bid = (int)(blockIdx.x % 8) * 160 + (int)(blockIdx.x / 8);
  int rp = bid % 16; int ty = (bid / 16) % 5; int csel = (bid / 80) % 2; int b = bid / 160;
  int r0 = rp * 2;
  int kc0 = csel * 3;
  int tid = threadIdx.x;
  int lane = tid & 63; int wm = tid >> 6;          // 2 waves
  int l15 = lane & 15, kq = lane >> 4;

  f32x4 acc[2][5];
#pragma unroll
  for (int i = 0; i < 2; ++i)
#pragma unroll
    for (int j = 0; j < 5; ++j) acc[i][j] = (f32x4){0.f, 0.f, 0.f, 0.f};

  const u16* fb = featP + (size_t)b * PB;
  int rowg0 = 2 * r0 + ty;

  bf16x8 r[6];
  auto load_chunk = [&](int kc) {
#pragma unroll
    for (int it = 0; it < 6; ++it) {
      int idx = it * 128 + tid;
      if (idx < 672) {
        int slot = idx & 3; int q = (idx >> 2) % 84; int row = idx / 336;
        r[it] = *(const bf16x8*)(fb + ((size_t)(rowg0 + 2 * row) * WP + q) * KC + kc * 32 + slot * 8);
      }
    }
  };
  auto write_chunk = [&](int buf) {
    char* lw = (char*)lds[buf];
#pragma unroll
    for (int it = 0; it < 6; ++it) {
      int idx = it * 128 + tid;
      if (idx < 672) {
        int q = (idx >> 2) % 84;
        int byte = (idx * 16) ^ ((q & 7) << 4);
        *(bf16x8*)(lw + byte) = r[it];
      }
    }
  };

  load_chunk(kc0);
  write_chunk(0);
  __syncthreads();

#pragma unroll
  for (int k = 0; k < 3; ++k) {
    int kc = kc0 + k;
    if (k < 2) load_chunk(kc + 1);
    const char* lb = (const char*)lds[k & 1];
#pragma unroll
    for (int tx = 0; tx < 5; ++tx) {
      bf16x8 av[2], bv[5];
#pragma unroll
      for (int fm = 0; fm < 2; ++fm)
        av[fm] = *(const bf16x8*)(A5 + ((size_t)((ty * 5 + tx) * 64 + wm * 32 + fm * 16 + l15)) * 192 + kc * 32 + kq * 8);
#pragma unroll
      for (int fn = 0; fn < 5; ++fn) {
        int p = fn * 16 + l15;
        int orow = p / 40, ocol = p % 40;
        int q = ocol * 2 + tx;
        int byte = (((orow * 84 + q) * 4 + kq) * 16) ^ ((q & 7) << 4);
        bv[fn] = *(const bf16x8*)(lb + byte);
      }
      __builtin_amdgcn_s_setprio(1);
#pragma unroll
      for (int fm = 0; fm < 2; ++fm)
#pragma unroll
        for (int fn = 0; fn < 5; ++fn)
          acc[fm][fn] = __builtin_amdgcn_mfma_f32_16x16x32_bf16(av[fm], bv[fn], acc[fm][fn], 0, 0, 0);
      __builtin_amdgcn_s_setprio(0);
    }
    if (k < 2) {
      write_chunk((k + 1) & 1);
      __syncthreads();
    }
  }
  int slot10 = csel * 5 + ty;
#pragma unroll
  for (int fm = 0; fm < 2; ++fm) {
    int oc0 = wm * 32 + fm * 16 + kq * 4;
#pragma unroll
    for (int fn = 0; fn < 5; ++fn) {
      int p = fn * 16 + l15;
      int orow = r0 + p / 40, ocol = p % 40;
      u16* dst = pa + (((((size_t)slot10 * B + b) * 32 + orow) * 40 + ocol) * 64) + oc0;
      uint2 pkv;
      pkv.x = pk2(f2b(acc[fm][fn][0]), f2b(acc[fm][fn][1]));
      pkv.y = pk2(f2b(acc[fm][fn][2]), f2b(acc[fm][fn][3]));
      *(uint2*)dst = pkv;
    }
  }
}

// ---------------- combine 10 bf16 partials -> relu -> bf16 haP ----------------
__global__ void combine10(const u16* __restrict__ pa, u16* __restrict__ haP) {
  int idx = blockIdx.x * blockDim.x + threadIdx.x;
  if (idx >= B * 32 * 40 * 8) return;
  int c8 = idx & 7; int t = idx >> 3;
  int ocol = t % 40; t /= 40; int orow = t % 32; int b = t / 32;
  float s[8];
#pragma unroll
  for (int k = 0; k < 8; ++k) s[k] = 0.f;
#pragma unroll
  for (int sl = 0; sl < 10; ++sl) {
    const u16* p = pa + ((((size_t)sl * B + b) * 32 + orow) * 40 + ocol) * 64 + c8 * 8;
    uint4 v = *(const uint4*)p;
    s[0] += blo(v.x); s[1] += bhi(v.x); s[2] += blo(v.y); s[3] += bhi(v.y);
    s[4] += blo(v.z); s[5] += bhi(v.z); s[6] += blo(v.w); s[7] += bhi(v.w);
  }
  uint4 o;
  o.x = pk2(f2b(fmaxf(s[0], 0.f)), f2b(fmaxf(s[1], 0.f)));
  o.y = pk2(f2b(fmaxf(s[2], 0.f)), f2b(fmaxf(s[3], 0.f)));
  o.z = pk2(f2b(fmaxf(s[4], 0.f)), f2b(fmaxf(s[5], 0.f)));
  o.w = pk2(f2b(fmaxf(s[6], 0.f)), f2b(fmaxf(s[7], 0.f)));
  *(uint4*)(haP + ((size_t)(b * HA + orow + 2) * WA + (ocol + 2)) * 64 + c8 * 8) = o;
}

// ---------------- MFMA implicit-GEMM conv (conv5b), fp32 NCHW out ----------------
template<int TY, int TX, int S, int OH, int OW, int M, int BM, int BN, int POFF,
         int KCIN, int HPIN, int WPIN>
__global__ __launch_bounds__(256) void gemm_conv(
    const u16* __restrict__ A, const u16* __restrict__ featP,
    float* __restrict__ outF, int MT, int NT) {
  constexpr int WM = BM / 2, WN = BN / 2, FM = WM / 16, FN = WN / 16;
  constexpr int NKC = KCIN / 32;
  int nwg = gridDim.x;
  int bid = (int)(blockIdx.x % 8) * (nwg / 8) + (int)(blockIdx.x / 8);
  int mt = bid % MT; int rest = bid / MT; int nt = rest % NT; int b = rest / NT;
  int lane = threadIdx.x & 63; int wv = threadIdx.x >> 6;
  int wm = wv >> 1, wn = wv & 1;
  int l15 = lane & 15, kq = lane >> 4;

  f32x4 acc[FM][FN];
#pragma unroll
  for (int i = 0; i < FM; ++i)
#pragma unroll
    for (int j = 0; j < FN; ++j) acc[i][j] = (f32x4){0.f, 0.f, 0.f, 0.f};

  const u16* Abase = A + (size_t)(mt * BM + wm * WM + l15) * KCIN + kq * 8;
  const u16* fb = featP + (size_t)b * (HPIN * WPIN * KCIN) + kq * 8;

  int ohh[FN], oww[FN];
#pragma unroll
  for (int fn = 0; fn < FN; ++fn) {
    int p = nt * BN + wn * WN + fn * 16 + l15;
    ohh[fn] = p / OW; oww[fn] = p % OW;
  }

  for (int kc = 0; kc < NKC; ++kc) {
    for (int ty = 0; ty < TY; ++ty)
      for (int tx = 0; tx < TX; ++tx) {
        const u16* At = Abase + (size_t)((ty * TX + tx) * M) * KCIN + kc * 32;
        bf16x8 av[FM], bv[FN];
#pragma unroll
        for (int fm = 0; fm < FM; ++fm)
          av[fm] = *(const bf16x8*)(At + fm * 16 * KCIN);
#pragma unroll
        for (int fn = 0; fn < FN; ++fn) {
          int hi = ohh[fn] * S + ty + POFF;
          int wi = oww[fn] * S + tx + POFF;
          bv[fn] = *(const bf16x8*)(fb + (size_t)(hi * WPIN + wi) * KCIN + kc * 32);
        }
#pragma unroll
        for (int fm = 0; fm < FM; ++fm)
#pragma unroll
          for (int fn = 0; fn < FN; ++fn)
            acc[fm][fn] = __builtin_amdgcn_mfma_f32_16x16x32_bf16(av[fm], bv[fn], acc[fm][fn], 0, 0, 0);
      }
  }

#pragma unroll
  for (int fm = 0; fm < FM; ++fm) {
    int oc0 = mt * BM + wm * WM + fm * 16 + kq * 4;
#pragma unroll
    for (int fn = 0; fn < FN; ++fn) {
#pragma unroll
      for (int r = 0; r < 4; ++r) {
        float v = fmaxf(acc[fm][fn][r], 0.f);
        outF[(((size_t)b * M + oc0 + r) * OH + ohh[fn]) * OW + oww[fn]] = v;
      }
    }
  }
}

// ---------------- conv3+mean fold, step 1: 9-bin tap sums (wave reduce, no atomics) ----------------
__global__ void tapsum_kernel(const float* __restrict__ hb, float* __restrict__ Sm) {
  int b = blockIdx.x >> 6; int ic = blockIdx.x & 63; int lane = threadIdx.x;
  const float* p = hb + ((size_t)(b * 64 + ic)) * 320;
  float s[9];
#pragma unroll
  for (int t = 0; t < 9; ++t) s[t] = 0.f;
  for (int i = lane; i < 320; i += 64) {
    int ih = i / 20, iw = i % 20;
    float v = p[i];
#pragma unroll
    for (int ky = 0; ky < 3; ++ky) {
      int t2 = ih + 1 - ky;
      if (t2 < 0 || t2 > 14 || (t2 & 1)) continue;
#pragma unroll
      for (int kx = 0; kx < 3; ++kx) {
        int t3 = iw + 1 - kx;
        if (t3 < 0 || t3 > 18 || (t3 & 1)) continue;
        s[ky * 3 + kx] += v;
      }
    }
  }
#pragma unroll
  for (int t = 0; t < 9; ++t)
#pragma unroll
    for (int off = 32; off > 0; off >>= 1) s[t] += __shfl_down(s[t], off);
  if (lane == 0) {
#pragma unroll
    for (int t = 0; t < 9; ++t) Sm[(b * 64 + ic) * 9 + t] = s[t];
  }
}

// ---------------- fv GEMV (branch 1) ----------------
__global__ void gemv_fv(const float* __restrict__ w3, const float* __restrict__ Sm,
                        float* __restrict__ fv, int OC) {
  int o = blockIdx.x % OC; int b = blockIdx.x / OC; int lane = threadIdx.x;
  const float* wp = w3 + ((size_t)o * 64 + lane) * 9;
  const float* sp = Sm + ((size_t)b * 64 + lane) * 9;
  float acc = 0.f;
#pragma unroll
  for (int t = 0; t < 9; ++t) acc += wp[t] * sp[t];
#pragma unroll
  for (int off = 32; off > 0; off >>= 1) acc += __shfl_down(acc, off);
  if (lane == 0) fv[b * OC + o] = acc * (1.0f / 80.0f);
}

// ---------------- branch-2 gemv fused with final output ----------------
__global__ void gemv_final(const float* __restrict__ w3, const float* __restrict__ Sm,
                           const float* __restrict__ ww, const float* __restrict__ wb,
                           float* __restrict__ out) {
  int o = blockIdx.x & 63; int b = blockIdx.x >> 6; int lane = threadIdx.x;
  const float* wp = w3 + ((size_t)o * 64 + lane) * 9;
  const float* sp = Sm + ((size_t)b * 64 + lane) * 9;
  float acc = 0.f;
#pragma unroll
  for (int t = 0; t < 9; ++t) acc += wp[t] * sp[t];
#pragma unroll
  for (int off = 32; off > 0; off >>= 1) acc += __shfl_down(acc, off);
  float fvv = __shfl(acc, 0) * (1.0f / 80.0f);
  const float* wwp = ww + (size_t)o * 576;
  const float* wbp = wb + (size_t)o * 576;
  float* op = out + ((size_t)(b * 64 + o)) * 576;
#pragma unroll
  for (int k = 0; k < 9; ++k)
    op[k * 64 + lane] = fvv * wwp[k * 64 + lane] + wbp[k * 64 + lane];
}

extern "C" void kernel_launch(void* const* d_in, const int* in_sizes, int n_in,
                              void* d_out, int out_size, void* d_ws, size_t ws_size,
                              hipStream_t stream) {
  const float* x0    = (const float*)d_in[0];
  const float* y0    = (const float*)d_in[1];
  const float* x     = (const float*)d_in[2];
  const float* y     = (const float*)d_in[3];
  const float* w1a   = (const float*)d_in[4];
  const float* w1b   = (const float*)d_in[5];
  const float* w1c   = (const float*)d_in[6];
  const float* w2a   = (const float*)d_in[7];
  const float* w2b   = (const float*)d_in[8];
  const float* w2c   = (const float*)d_in[9];
  const float* wx_w  = (const float*)d_in[10];
  const float* wx_b  = (const float*)d_in[11];
  const float* wxf_w = (const float*)d_in[12];
  const float* wxf_b = (const float*)d_in[13];
  float* out = (float*)d_out;

  char* base = (char*)d_ws;
  size_t off = 0;
  auto take = [&](size_t bytes) -> char* {
    char* p = base + off; off += (bytes + 255) & ~(size_t)255; return p;
  };
  u16*   featP1 = (u16*)take((size_t)B * PB * 2);                 // 17.55 MB
  u16*   featP2 = (u16*)take((size_t)B * PB * 2);                 // 17.55 MB
  u16*   paAwx  = (u16*)take((size_t)10 * B * 32 * 40 * 64 * 2);  // 13.1 MB
  u16*   pa     = paAwx;
  u16*   Apk    = paAwx;
  u16*   xpT    = paAwx;                                           // alias: pools consumed before pa written
  u16*   ypT    = paAwx + (size_t)B * H * W * C;
  u16*   A5a    = (u16*)take((size_t)25 * 64 * 192 * 2);
  u16*   A5b    = (u16*)take((size_t)25 * 64 * 192 * 2);
  u16*   A5b1   = (u16*)take((size_t)25 * 64 * 64 * 2);
  u16*   A5b2   = (u16*)take((size_t)25 * 64 * 64 * 2);
  u16*   haP    = (u16*)take((size_t)B * HA * WA * 64 * 2);
  float* hb     = (float*)take((size_t)B * 64 * 320 * 4);
  float* Sm     = (float*)take((size_t)B * 64 * 9 * 4);
  float* fv1    = (float*)take((size_t)B * CW * 4);
  if (off > ws_size) return;

  const int TB = 256;

  {
    int nsetup = (B * PB) / 8 + (B * HA * WA * 64) / 8 + B * 592 * 24
               + 2 * 25 * 64 * 192 + 2 * 25 * 64 * 64;
    int grid = 1024 + (nsetup + TB - 1) / TB;
    setup_pool<<<grid, TB, 0, stream>>>(x0, y0, xpT, ypT,
        w1a, w2a, w1b, w2b, A5a, A5b, A5b1, A5b2, featP1, haP, featP2);
  }
  corr_copy<<<512 + 1024, TB, 0, stream>>>(xpT, ypT, x, y, featP1);

  // ---- branch 1 ----
  conv5_split_kernel<<<1280, 128, 0, stream>>>(A5a, featP1, pa);
  combine10<<<(B * 32 * 40 * 8 + TB - 1) / TB, TB, 0, stream>>>(pa, haP);
  gemm_conv<5, 5, 2, 16, 20, 64, 32, 32, 0, 64, HA, WA>
      <<<160, TB, 0, stream>>>(A5b1, haP, hb, 2, 10);
  tapsum_kernel<<<B * 64, 64, 0, stream>>>(hb, Sm);
  gemv_fv<<<B * CW, 64, 0, stream>>>(w1c, Sm, fv1, CW);

  // ---- adaptive conv ----
  wx_pack<<<(9 * 192 * 24 + TB - 1) / TB, TB, 0, stream>>>(fv1, wx_w, wx_b, Apk);
  ad_conv_kernel<<<64 * B, 256, 0, stream>>>(Apk, featP1, featP2);

  // ---- branch 2 ----
  conv5_split_kernel<<<1280, 128, 0, stream>>>(A5b, featP2, pa);
  combine10<<<(B * 32 * 40 * 8 + TB - 1) / TB, TB, 0, stream>>>(pa, haP);
  gemm_conv<5, 5, 2, 16, 20, 64, 32, 32, 0, 64, HA, WA>
      <<<160, TB, 0, stream>>>(A5b2, haP, hb, 2, 10);
  tapsum_kernel<<<B * 64, 64, 0, stream>>>(hb, Sm);
  gemv_final<<<B * 64, 64, 0, stream>>>(w2c, Sm, wxf_w, wxf_b, out);
}